// Round 2
// baseline (410.548 us; speedup 1.0000x reference)
//
#include <hip/hip_runtime.h>
#include <math.h>

// ---------------------------------------------------------------------------
// DistanceBias fused kernel for MI355X (gfx950)
// out[b,h,i,j], B=2,H=32,N=1024, L=256 (ligand), P=768 (protein)
//   LL (i<L,j<L):    gelu(g@ow1+ob1)@ow2 + gelu(dlm@vw1+vb1)@vw2 + ob2+vb2
//   LP (i>=L,j<L):   same with row=protein point
//   PL (i<L,j>=L):   transpose of (ef_lp + gelu(-dlm@vw1+vb1)@vw2 + ...)
//   PP (i>=L,j>=L):  0
// Fast path (vb1==0, detected at runtime): gelu(-u)=gelu(u)-u =>
//   out_pl = out_lp - dlm @ (vw1@vw2)   (W3, 3x32, precomputed)
// Round 2: fast/general kernel split, LDS union (18.9KB), launch_bounds(256,4),
//          PP fill interleaved 16:9 with compute blocks, cheaper bf16 round.
// ---------------------------------------------------------------------------

typedef __attribute__((__ext_vector_type__(8))) short bfrag;   // 8 x bf16 bits
typedef __attribute__((__ext_vector_type__(4))) float fx4;

#define MFMA_BF16(A, B, C) __builtin_amdgcn_mfma_f32_16x16x32_bf16((A), (B), (C), 0, 0, 0)

// workspace layout (float offsets)
#define OFF_ISTD 0      // 128: 1/(|std|+1e-5)
#define OFF_MS   128    // 128: mean * istd
#define OFF_C2   256    // 128: istd / sqrt(2*pi)
#define OFF_BIAS 384    // 32 : ob2 + vb2
#define OFF_W3   416    // 96 : W3[c][h] = sum_k vw1[c][k]*vw2[k][h]
#define OFF_FLAG 512    // 1  : int, 1 if vb1 all zero
#define WS_H_BASE 1024  // ushort region starts at float offset 1024
#define HOFF_OW1 0      // 16384 ushort, B-frag swizzled
#define HOFF_OW2 16384  // 4096
#define HOFF_VW2 20480  // 4096

#define N_MAIN 4096     // 1024 LL tiles + 3072 LP tiles
#define N_PP   2304     // zero-fill blocks
#define PP_ITERS 16
#define N_TOTAL (N_MAIN + N_PP)

__device__ __forceinline__ float rcp_f(float x) {
#if __has_builtin(__builtin_amdgcn_rcpf)
  return __builtin_amdgcn_rcpf(x);
#else
  return 1.0f / x;
#endif
}
__device__ __forceinline__ float exp2_f(float x) {
#if __has_builtin(__builtin_amdgcn_exp2f)
  return __builtin_amdgcn_exp2f(x);
#else
  return exp2f(x);
#endif
}
__device__ __forceinline__ unsigned short f2bf(float f) {  // RNE (setup only)
  unsigned u = __builtin_bit_cast(unsigned, f);
  return (unsigned short)((u + 0x7fffu + ((u >> 16) & 1u)) >> 16);
}
__device__ __forceinline__ unsigned short f2bf_fast(float f) {  // round-half-up, <=0.5 ulp
  unsigned u = __builtin_bit_cast(unsigned, f);
  return (unsigned short)((u + 0x8000u) >> 16);
}
// tanh-free GELU via sigmoid form: x / (1 + exp2(-x*(a + b x^2)*log2e*2))
__device__ __forceinline__ float gelu_t(float x) {
  float z = x * x;
  float p = x * __builtin_fmaf(z, -0.10294324f, -2.30220821f);  // -2u*log2(e)
  float e = exp2_f(p);
  return x * rcp_f(1.0f + e);
}

// ---------------------------------------------------------------------------
__global__ void setup_kernel(const float* __restrict__ means, const float* __restrict__ stds,
                             const float* __restrict__ ow1, const float* __restrict__ ow2,
                             const float* __restrict__ vw1, const float* __restrict__ vw2,
                             const float* __restrict__ ob2, const float* __restrict__ vb2,
                             const float* __restrict__ vb1, float* __restrict__ wsf) {
  int id = blockIdx.x * 256 + threadIdx.x;  // grid 16 -> 4096 threads
  unsigned short* wsh = (unsigned short*)(wsf + WS_H_BASE);

  if (id < 128) {
    float s = fabsf(stds[id]) + 1e-5f;
    float inv = 1.0f / s;
    wsf[OFF_ISTD + id] = inv;
    wsf[OFF_MS + id] = means[id] * inv;
    wsf[OFF_C2 + id] = inv * 0.3989422804f;  // 1/sqrt(2*pi)
  } else if (id < 160) {
    int h = id - 128;
    wsf[OFF_BIAS + h] = ob2[h] + vb2[h];
  } else if (id < 256) {
    int t = id - 160; int c = t >> 5, h = t & 31;
    float s = 0.0f;
    for (int k = 0; k < 128; ++k) s += vw1[c * 128 + k] * vw2[k * 32 + h];
    wsf[OFF_W3 + c * 32 + h] = s;
  } else if (id == 256) {
    int f = 1;
    for (int k = 0; k < 128; ++k) if (vb1[k] != 0.0f) f = 0;
    ((int*)wsf)[OFF_FLAG] = f;
  }
  // ow1 (128x128) -> B-frag layout: block=(n>>4)*4+(k>>5); in-block ((n&15)*4+((k>>3)&3))*8+(k&7)
  for (int idx = id; idx < 16384; idx += 4096) {
    int k = idx >> 7, n = idx & 127;
    int pos = ((n >> 4) * 4 + (k >> 5)) * 512 + ((n & 15) * 4 + ((k >> 3) & 3)) * 8 + (k & 7);
    wsh[HOFF_OW1 + pos] = f2bf(ow1[idx]);
  }
  // ow2 / vw2 (128x32)
  {
    int idx = id;  // exactly 4096 elements
    int k = idx >> 5, n = idx & 31;
    int pos = ((n >> 4) * 4 + (k >> 5)) * 512 + ((n & 15) * 4 + ((k >> 3) & 3)) * 8 + (k & 7);
    wsh[HOFF_OW2 + pos] = f2bf(ow2[idx]);
    wsh[HOFF_VW2 + pos] = f2bf(vw2[idx]);
  }
}

// ---------------------------------------------------------------------------
// decode interleaved block index: per group of 25 -> 16 main, 9 PP
__device__ __forceinline__ void decode_block(int bidx, bool& is_pp, int& sub) {
  int g = bidx / 25, r = bidx % 25;   // 256 groups
  if (r >= 16) { is_pp = true;  sub = g * 9 + (r - 16); }
  else         { is_pp = false; sub = g * 16 + r; }
}

__device__ __forceinline__ void pp_fill(int pp_id, float* __restrict__ out, int tid) {
  int id = pp_id * 256 + tid;  // 0..589823
  fx4 z = {0.f, 0.f, 0.f, 0.f};
#pragma unroll
  for (int i = 0; i < PP_ITERS; ++i) {
    int idx = id + i * 589824;          // total 9437184 float4s
    int c4 = idx % 192;
    int t2 = idx / 192;
    int r = t2 % 768;
    int bh = t2 / 768;                  // 0..63
    *(fx4*)(out + (((long)bh) << 20) + ((long)(256 + r) << 10) + 256 + c4 * 4) = z;
  }
}

// ---------------------------------------------------------------------------
// FAST kernel: requires vb1 == 0 (flag==1); else exits immediately.
__global__ __launch_bounds__(256, 4) void main_fast(
    const float* __restrict__ pos, const int* __restrict__ etyp,
    const float* __restrict__ mulw, const float* __restrict__ biasw,
    const float* __restrict__ ob1, const float* __restrict__ vw1,
    const float* __restrict__ wsf, float* __restrict__ out) {
  int flag = ((const int*)wsf)[OFF_FLAG];
  if (!flag) return;

  int tid = threadIdx.x;
  bool is_pp; int sub;
  decode_block(blockIdx.x, is_pp, sub);
  if (is_pp) { pp_fill(sub, out, tid); return; }

  const unsigned short* wsh = (const unsigned short*)(wsf + WS_H_BASE);
  __shared__ union {
    struct { unsigned short hef[4096]; unsigned short hlp[4096]; } s;
    float outb[4224];                   // [h][e] staging, stride 132 (after c2 loop)
  } u;
  __shared__ float dlmb[512];           // dlm per edge (stride 4)

  int lane = tid & 63, w = tid >> 6;
  int q = lane >> 4, c15 = lane & 15;

  // tile decode: 128 edges = 8 rows x 16 cols
  int t = sub;
  int b, row0, col0;
  bool is_lp;
  if (t < 1024) {
    is_lp = false;
    b = t >> 9;
    int r = t & 511;                       // 32 row-tiles x 16 col-tiles
    row0 = (r >> 4) << 3;
    col0 = (r & 15) << 4;
  } else {
    is_lp = true;
    int t2 = t - 1024;
    b = t2 / 1536;
    int r = t2 % 1536;                     // 96 x 16
    row0 = 256 + ((r >> 4) << 3);
    col0 = (r & 15) << 4;
  }

  // ---- stage 1: gaussians directly into MFMA A-fragments (registers) ----
  bfrag gfr[2][4];
  float Ae[2];
  for (int mi = 0; mi < 2; ++mi) {
    int rloc = 2 * w + mi;
    int rowg = row0 + rloc, colg = col0 + c15;
    const float* pr = pos + ((b << 10) + rowg) * 3;
    const float* pc = pos + ((b << 10) + colg) * 3;
    float dx = pc[0] - pr[0], dy = pc[1] - pr[1], dz = pc[2] - pr[2];
    float d2 = __builtin_fmaf(dx, dx, __builtin_fmaf(dy, dy, dz * dz));
    float dist = rcp_f(d2 + 1.0f);
    int et = etyp[(b << 20) + (rowg << 10) + colg];
    Ae[mi] = __builtin_fmaf(mulw[et], dist, biasw[et]);
    if (q == 0) {
      int e = rloc * 16 + c15;
      dlmb[e * 4 + 0] = dx; dlmb[e * 4 + 1] = dy; dlmb[e * 4 + 2] = dz;
    }
  }
#pragma unroll
  for (int kc = 0; kc < 4; ++kc) {
    int k0 = kc * 32 + q * 8;
    fx4 is0 = *(const fx4*)(wsf + OFF_ISTD + k0);
    fx4 is1 = *(const fx4*)(wsf + OFF_ISTD + k0 + 4);
    fx4 ms0 = *(const fx4*)(wsf + OFF_MS + k0);
    fx4 ms1 = *(const fx4*)(wsf + OFF_MS + k0 + 4);
    fx4 cc0 = *(const fx4*)(wsf + OFF_C2 + k0);
    fx4 cc1 = *(const fx4*)(wsf + OFF_C2 + k0 + 4);
#pragma unroll
    for (int mi = 0; mi < 2; ++mi) {
      bfrag fr;
#pragma unroll
      for (int j = 0; j < 8; ++j) {
        float is = (j < 4) ? is0[j & 3] : is1[j & 3];
        float msv = (j < 4) ? ms0[j & 3] : ms1[j & 3];
        float ccv = (j < 4) ? cc0[j & 3] : cc1[j & 3];
        float y = __builtin_fmaf(Ae[mi], is, -msv);
        float g = exp2_f(y * y * (-0.72134752f)) * ccv;  // exp(-0.5 y^2)
        fr[j] = (short)f2bf_fast(g);
      }
      gfr[mi][kc] = fr;
    }
  }
  __syncthreads();  // dlmb visible

  float ob1v[8];
#pragma unroll
  for (int i = 0; i < 8; ++i) ob1v[i] = ob1[i * 16 + c15];

  fx4 zero4 = {0.f, 0.f, 0.f, 0.f};
  fx4 aef[2][2], alp[2][2];
#pragma unroll
  for (int mi = 0; mi < 2; ++mi)
#pragma unroll
    for (int nh = 0; nh < 2; ++nh) { aef[mi][nh] = zero4; alp[mi][nh] = zero4; }

  int oct = tid & 3, e0 = tid >> 2;

  // ---- main loop over kk (hidden dim) chunks of 32 ----
  for (int c2 = 0; c2 < 4; ++c2) {
    // GEMM1: hidden[e][kk] for this chunk
    fx4 a1[2][2];
#pragma unroll
    for (int mi = 0; mi < 2; ++mi) { a1[mi][0] = zero4; a1[mi][1] = zero4; }
#pragma unroll
    for (int kc = 0; kc < 4; ++kc) {
      bfrag b0 = *(const bfrag*)(wsh + HOFF_OW1 + (((c2 * 2 + 0) * 4 + kc) * 512 + (c15 * 4 + q) * 8));
      bfrag b1 = *(const bfrag*)(wsh + HOFF_OW1 + (((c2 * 2 + 1) * 4 + kc) * 512 + (c15 * 4 + q) * 8));
      a1[0][0] = MFMA_BF16(gfr[0][kc], b0, a1[0][0]);
      a1[0][1] = MFMA_BF16(gfr[0][kc], b1, a1[0][1]);
      a1[1][0] = MFMA_BF16(gfr[1][kc], b0, a1[1][0]);
      a1[1][1] = MFMA_BF16(gfr[1][kc], b1, a1[1][1]);
    }
    // gelu(+ob1) -> bf16 scatter to LDS in A2-frag layout
#pragma unroll
    for (int mi = 0; mi < 2; ++mi)
#pragma unroll
      for (int nt = 0; nt < 2; ++nt) {
        float bb = ob1v[c2 * 2 + nt];
#pragma unroll
        for (int r = 0; r < 4; ++r) {
          float v = gelu_t(a1[mi][nt][r] + bb);
          u.s.hef[(2 * w + mi) * 512 + ((q * 4 + r) * 4 + nt * 2 + ((lane >> 3) & 1)) * 8 + (lane & 7)] = f2bf_fast(v);
        }
      }
    // dlm-MLP hidden for this chunk (VALU; 3-wide K)
    {
      int kk0 = c2 * 32 + oct * 8;
      fx4 w1a0 = *(const fx4*)(vw1 + kk0);
      fx4 w1a1 = *(const fx4*)(vw1 + kk0 + 4);
      fx4 w1b0 = *(const fx4*)(vw1 + 128 + kk0);
      fx4 w1b1 = *(const fx4*)(vw1 + 128 + kk0 + 4);
      fx4 w1c0 = *(const fx4*)(vw1 + 256 + kk0);
      fx4 w1c1 = *(const fx4*)(vw1 + 256 + kk0 + 4);
#pragma unroll
      for (int pass = 0; pass < 2; ++pass) {
        int e = e0 + (pass << 6);
        float dx = dlmb[e * 4 + 0], dy = dlmb[e * 4 + 1], dz = dlmb[e * 4 + 2];
        bfrag fl;
#pragma unroll
        for (int j = 0; j < 8; ++j) {
          float wa = (j < 4) ? w1a0[j & 3] : w1a1[j & 3];
          float wb = (j < 4) ? w1b0[j & 3] : w1b1[j & 3];
          float wc = (j < 4) ? w1c0[j & 3] : w1c1[j & 3];
          float u0 = __builtin_fmaf(dx, wa, __builtin_fmaf(dy, wb, dz * wc));
          fl[j] = (short)f2bf_fast(gelu_t(u0));
        }
        *((bfrag*)(u.s.hlp + (e >> 4) * 512 + ((e & 15) * 4 + oct) * 8)) = fl;
      }
    }
    __syncthreads();
    // GEMM2: accumulate 32-wide kk chunk into H=32 outputs
#pragma unroll
    for (int mi = 0; mi < 2; ++mi) {
      int mt = 2 * w + mi;
      bfrag a_ef = *(const bfrag*)(u.s.hef + mt * 512 + (c15 * 4 + q) * 8);
      bfrag a_lp = *(const bfrag*)(u.s.hlp + mt * 512 + (c15 * 4 + q) * 8);
#pragma unroll
      for (int nh = 0; nh < 2; ++nh) {
        bfrag b_o = *(const bfrag*)(wsh + HOFF_OW2 + ((nh * 4 + c2) * 512 + (c15 * 4 + q) * 8));
        bfrag b_v = *(const bfrag*)(wsh + HOFF_VW2 + ((nh * 4 + c2) * 512 + (c15 * 4 + q) * 8));
        aef[mi][nh] = MFMA_BF16(a_ef, b_o, aef[mi][nh]);
        alp[mi][nh] = MFMA_BF16(a_lp, b_v, alp[mi][nh]);
      }
    }
    __syncthreads();  // protect hef/hlp before next chunk overwrites
  }

  // ---- epilogue: out_lp = aef + alp + (ob2+vb2), staged via LDS [h][e] ----
  float bs0 = wsf[OFF_BIAS + c15];
  float bs1 = wsf[OFF_BIAS + 16 + c15];
#pragma unroll
  for (int mi = 0; mi < 2; ++mi) {
    int mt = 2 * w + mi;
#pragma unroll
    for (int nh = 0; nh < 2; ++nh) {
      float bb = nh ? bs1 : bs0;
      fx4 v;
#pragma unroll
      for (int r = 0; r < 4; ++r) v[r] = aef[mi][nh][r] + alp[mi][nh][r] + bb;
      *(fx4*)(u.outb + (nh * 16 + c15) * 132 + mt * 16 + q * 4) = v;
    }
  }
  __syncthreads();

  long base = (((long)(b * 32)) << 20) + (((long)row0) << 10) + col0;
#pragma unroll
  for (int i = 0; i < 4; ++i) {
    int it = tid + (i << 8);
    int h = it >> 5, rr = (it >> 2) & 7, c4v = it & 3;
    fx4 v = *(const fx4*)(u.outb + h * 132 + rr * 16 + c4v * 4);
    *(fx4*)(out + base + (((long)h) << 20) + (rr << 10) + c4v * 4) = v;
  }

  if (is_lp) {
    // fast PL: out_pl = out_lp - dlm @ W3 (transposed write)
#pragma unroll
    for (int i = 0; i < 4; ++i) {
      int it = tid + (i << 8);
      int h = it >> 5, rr2 = (it >> 1) & 15, p4 = it & 1;
      float w30 = wsf[OFF_W3 + h];
      float w31 = wsf[OFF_W3 + 32 + h];
      float w32 = wsf[OFF_W3 + 64 + h];
      fx4 v;
#pragma unroll
      for (int k = 0; k < 4; ++k) {
        int e = (p4 * 4 + k) * 16 + rr2;
        float val = u.outb[h * 132 + e];
        float dx = dlmb[e * 4 + 0], dy = dlmb[e * 4 + 1], dz = dlmb[e * 4 + 2];
        v[k] = val - __builtin_fmaf(dx, w30, __builtin_fmaf(dy, w31, dz * w32));
      }
      *(fx4*)(out + (((long)(b * 32 + h)) << 20) + (((long)(col0 + rr2)) << 10) + row0 + p4 * 4) = v;
    }
  }
}

// ---------------------------------------------------------------------------
// GENERAL kernel: handles vb1 != 0 (flag==0); else exits immediately.
__global__ __launch_bounds__(256, 2) void main_general(
    const float* __restrict__ pos, const int* __restrict__ etyp,
    const float* __restrict__ mulw, const float* __restrict__ biasw,
    const float* __restrict__ ob1, const float* __restrict__ vw1,
    const float* __restrict__ vb1, const float* __restrict__ wsf,
    float* __restrict__ out) {
  int flag = ((const int*)wsf)[OFF_FLAG];
  if (flag) return;

  int tid = threadIdx.x;
  if (blockIdx.x >= N_MAIN) { pp_fill(blockIdx.x - N_MAIN, out, tid); return; }

  const unsigned short* wsh = (const unsigned short*)(wsf + WS_H_BASE);
  __shared__ unsigned short hef[4096];
  __shared__ unsigned short hlp[4096];
  __shared__ unsigned short hpl[4096];
  __shared__ float dlmb[512];
  __shared__ float outb[4224];

  int lane = tid & 63, w = tid >> 6;
  int q = lane >> 4, c15 = lane & 15;

  int t = blockIdx.x;
  int b, row0, col0;
  bool is_lp;
  if (t < 1024) {
    is_lp = false;
    b = t >> 9;
    int r = t & 511;
    row0 = (r >> 4) << 3;
    col0 = (r & 15) << 4;
  } else {
    is_lp = true;
    int t2 = t - 1024;
    b = t2 / 1536;
    int r = t2 % 1536;
    row0 = 256 + ((r >> 4) << 3);
    col0 = (r & 15) << 4;
  }

  bfrag gfr[2][4];
  float Ae[2];
  for (int mi = 0; mi < 2; ++mi) {
    int rloc = 2 * w + mi;
    int rowg = row0 + rloc, colg = col0 + c15;
    const float* pr = pos + ((b << 10) + rowg) * 3;
    const float* pc = pos + ((b << 10) + colg) * 3;
    float dx = pc[0] - pr[0], dy = pc[1] - pr[1], dz = pc[2] - pr[2];
    float d2 = __builtin_fmaf(dx, dx, __builtin_fmaf(dy, dy, dz * dz));
    float dist = rcp_f(d2 + 1.0f);
    int et = etyp[(b << 20) + (rowg << 10) + colg];
    Ae[mi] = __builtin_fmaf(mulw[et], dist, biasw[et]);
    if (q == 0) {
      int e = rloc * 16 + c15;
      dlmb[e * 4 + 0] = dx; dlmb[e * 4 + 1] = dy; dlmb[e * 4 + 2] = dz;
    }
  }
#pragma unroll
  for (int kc = 0; kc < 4; ++kc) {
    int k0 = kc * 32 + q * 8;
    fx4 is0 = *(const fx4*)(wsf + OFF_ISTD + k0);
    fx4 is1 = *(const fx4*)(wsf + OFF_ISTD + k0 + 4);
    fx4 ms0 = *(const fx4*)(wsf + OFF_MS + k0);
    fx4 ms1 = *(const fx4*)(wsf + OFF_MS + k0 + 4);
    fx4 cc0 = *(const fx4*)(wsf + OFF_C2 + k0);
    fx4 cc1 = *(const fx4*)(wsf + OFF_C2 + k0 + 4);
#pragma unroll
    for (int mi = 0; mi < 2; ++mi) {
      bfrag fr;
#pragma unroll
      for (int j = 0; j < 8; ++j) {
        float is = (j < 4) ? is0[j & 3] : is1[j & 3];
        float msv = (j < 4) ? ms0[j & 3] : ms1[j & 3];
        float ccv = (j < 4) ? cc0[j & 3] : cc1[j & 3];
        float y = __builtin_fmaf(Ae[mi], is, -msv);
        float g = exp2_f(y * y * (-0.72134752f)) * ccv;
        fr[j] = (short)f2bf(g);
      }
      gfr[mi][kc] = fr;
    }
  }
  __syncthreads();

  float ob1v[8];
#pragma unroll
  for (int i = 0; i < 8; ++i) ob1v[i] = ob1[i * 16 + c15];

  fx4 zero4 = {0.f, 0.f, 0.f, 0.f};
  fx4 aef[2][2], alp[2][2], apl[2][2];
#pragma unroll
  for (int mi = 0; mi < 2; ++mi)
#pragma unroll
    for (int nh = 0; nh < 2; ++nh) { aef[mi][nh] = zero4; alp[mi][nh] = zero4; apl[mi][nh] = zero4; }

  int oct = tid & 3, e0 = tid >> 2;

  for (int c2 = 0; c2 < 4; ++c2) {
    fx4 a1[2][2];
#pragma unroll
    for (int mi = 0; mi < 2; ++mi) { a1[mi][0] = zero4; a1[mi][1] = zero4; }
#pragma unroll
    for (int kc = 0; kc < 4; ++kc) {
      bfrag b0 = *(const bfrag*)(wsh + HOFF_OW1 + (((c2 * 2 + 0) * 4 + kc) * 512 + (c15 * 4 + q) * 8));
      bfrag b1 = *(const bfrag*)(wsh + HOFF_OW1 + (((c2 * 2 + 1) * 4 + kc) * 512 + (c15 * 4 + q) * 8));
      a1[0][0] = MFMA_BF16(gfr[0][kc], b0, a1[0][0]);
      a1[0][1] = MFMA_BF16(gfr[0][kc], b1, a1[0][1]);
      a1[1][0] = MFMA_BF16(gfr[1][kc], b0, a1[1][0]);
      a1[1][1] = MFMA_BF16(gfr[1][kc], b1, a1[1][1]);
    }
#pragma unroll
    for (int mi = 0; mi < 2; ++mi)
#pragma unroll
      for (int nt = 0; nt < 2; ++nt) {
        float bb = ob1v[c2 * 2 + nt];
#pragma unroll
        for (int r = 0; r < 4; ++r) {
          float v = gelu_t(a1[mi][nt][r] + bb);
          hef[(2 * w + mi) * 512 + ((q * 4 + r) * 4 + nt * 2 + ((lane >> 3) & 1)) * 8 + (lane & 7)] = f2bf(v);
        }
      }
    {
      int kk0 = c2 * 32 + oct * 8;
      fx4 w1a0 = *(const fx4*)(vw1 + kk0);
      fx4 w1a1 = *(const fx4*)(vw1 + kk0 + 4);
      fx4 w1b0 = *(const fx4*)(vw1 + 128 + kk0);
      fx4 w1b1 = *(const fx4*)(vw1 + 128 + kk0 + 4);
      fx4 w1c0 = *(const fx4*)(vw1 + 256 + kk0);
      fx4 w1c1 = *(const fx4*)(vw1 + 256 + kk0 + 4);
      fx4 vb0 = *(const fx4*)(vb1 + kk0);
      fx4 vb1q = *(const fx4*)(vb1 + kk0 + 4);
#pragma unroll
      for (int pass = 0; pass < 2; ++pass) {
        int e = e0 + (pass << 6);
        float dx = dlmb[e * 4 + 0], dy = dlmb[e * 4 + 1], dz = dlmb[e * 4 + 2];
        bfrag fl, fp;
#pragma unroll
        for (int j = 0; j < 8; ++j) {
          float wa = (j < 4) ? w1a0[j & 3] : w1a1[j & 3];
          float wb = (j < 4) ? w1b0[j & 3] : w1b1[j & 3];
          float wc = (j < 4) ? w1c0[j & 3] : w1c1[j & 3];
          float bb = (j < 4) ? vb0[j & 3] : vb1q[j & 3];
          float u0 = __builtin_fmaf(dx, wa, __builtin_fmaf(dy, wb, dz * wc));
          fl[j] = (short)f2bf(gelu_t(u0 + bb));
          fp[j] = (short)f2bf(gelu_t(bb - u0));
        }
        *((bfrag*)(hlp + (e >> 4) * 512 + ((e & 15) * 4 + oct) * 8)) = fl;
        *((bfrag*)(hpl + (e >> 4) * 512 + ((e & 15) * 4 + oct) * 8)) = fp;
      }
    }
    __syncthreads();
#pragma unroll
    for (int mi = 0; mi < 2; ++mi) {
      int mt = 2 * w + mi;
      bfrag a_ef = *(const bfrag*)(hef + mt * 512 + (c15 * 4 + q) * 8);
      bfrag a_lp = *(const bfrag*)(hlp + mt * 512 + (c15 * 4 + q) * 8);
      bfrag a_pl = *(const bfrag*)(hpl + mt * 512 + (c15 * 4 + q) * 8);
#pragma unroll
      for (int nh = 0; nh < 2; ++nh) {
        bfrag b_o = *(const bfrag*)(wsh + HOFF_OW2 + ((nh * 4 + c2) * 512 + (c15 * 4 + q) * 8));
        bfrag b_v = *(const bfrag*)(wsh + HOFF_VW2 + ((nh * 4 + c2) * 512 + (c15 * 4 + q) * 8));
        aef[mi][nh] = MFMA_BF16(a_ef, b_o, aef[mi][nh]);
        alp[mi][nh] = MFMA_BF16(a_lp, b_v, alp[mi][nh]);
        apl[mi][nh] = MFMA_BF16(a_pl, b_v, apl[mi][nh]);
      }
    }
    __syncthreads();
  }

  float bs0 = wsf[OFF_BIAS + c15];
  float bs1 = wsf[OFF_BIAS + 16 + c15];
#pragma unroll
  for (int mi = 0; mi < 2; ++mi) {
    int mt = 2 * w + mi;
#pragma unroll
    for (int nh = 0; nh < 2; ++nh) {
      float bb = nh ? bs1 : bs0;
      fx4 v;
#pragma unroll
      for (int r = 0; r < 4; ++r) v[r] = aef[mi][nh][r] + alp[mi][nh][r] + bb;
      *(fx4*)(outb + (nh * 16 + c15) * 132 + mt * 16 + q * 4) = v;
    }
  }
  __syncthreads();

  long base = (((long)(b * 32)) << 20) + (((long)row0) << 10) + col0;
#pragma unroll
  for (int i = 0; i < 4; ++i) {
    int it = tid + (i << 8);
    int h = it >> 5, rr = (it >> 2) & 7, c4v = it & 3;
    fx4 v = *(const fx4*)(outb + h * 132 + rr * 16 + c4v * 4);
    *(fx4*)(out + base + (((long)h) << 20) + (rr << 10) + c4v * 4) = v;
  }

  if (is_lp) {
    __syncthreads();
#pragma unroll
    for (int mi = 0; mi < 2; ++mi) {
      int mt = 2 * w + mi;
#pragma unroll
      for (int nh = 0; nh < 2; ++nh) {
        float bb = nh ? bs1 : bs0;
        fx4 v;
#pragma unroll
        for (int r = 0; r < 4; ++r) v[r] = aef[mi][nh][r] + apl[mi][nh][r] + bb;
        *(fx4*)(outb + (nh * 16 + c15) * 132 + mt * 16 + q * 4) = v;
      }
    }
    __syncthreads();
#pragma unroll
    for (int i = 0; i < 4; ++i) {
      int it = tid + (i << 8);
      int h = it >> 5, rr2 = (it >> 1) & 15, p4 = it & 1;
      fx4 v;
#pragma unroll
      for (int k = 0; k < 4; ++k) {
        int e = (p4 * 4 + k) * 16 + rr2;
        v[k] = outb[h * 132 + e];
      }
      *(fx4*)(out + (((long)(b * 32 + h)) << 20) + (((long)(col0 + rr2)) << 10) + row0 + p4 * 4) = v;
    }
  }
}

// ---------------------------------------------------------------------------
extern "C" void kernel_launch(void* const* d_in, const int* in_sizes, int n_in,
                              void* d_out, int out_size, void* d_ws, size_t ws_size,
                              hipStream_t stream) {
  const float* pos   = (const float*)d_in[0];
  const int*   etyp  = (const int*)d_in[1];
  // d_in[2] = protein_length (768, fixed by harness shapes)
  const float* means = (const float*)d_in[3];
  const float* stds  = (const float*)d_in[4];
  const float* mulw  = (const float*)d_in[5];
  const float* biasw = (const float*)d_in[6];
  const float* ow1   = (const float*)d_in[7];
  const float* ob1   = (const float*)d_in[8];
  const float* ow2   = (const float*)d_in[9];
  const float* ob2   = (const float*)d_in[10];
  const float* vw1   = (const float*)d_in[11];
  const float* vb1   = (const float*)d_in[12];
  const float* vw2   = (const float*)d_in[13];
  const float* vb2   = (const float*)d_in[14];
  float* out = (float*)d_out;
  float* wsf = (float*)d_ws;

  setup_kernel<<<dim3(16), dim3(256), 0, stream>>>(means, stds, ow1, ow2, vw1, vw2,
                                                   ob2, vb2, vb1, wsf);
  main_fast<<<dim3(N_TOTAL), dim3(256), 0, stream>>>(pos, etyp, mulw, biasw,
                                                     ob1, vw1, wsf, out);
  main_general<<<dim3(N_TOTAL), dim3(256), 0, stream>>>(pos, etyp, mulw, biasw,
                                                        ob1, vw1, vb1, wsf, out);
}

// Round 3
// 384.691 us; speedup vs baseline: 1.0672x; 1.0672x over previous
//
#include <hip/hip_runtime.h>
#include <math.h>

// ---------------------------------------------------------------------------
// DistanceBias fused kernel for MI355X (gfx950)
// out[b,h,i,j], B=2,H=32,N=1024, L=256 (ligand), P=768 (protein)
//   LL (i<L,j<L):    gelu(g@ow1+ob1)@ow2 + gelu(dlm@vw1+vb1)@vw2 + ob2+vb2
//   LP (i>=L,j<L):   same with row=protein point
//   PL (i<L,j>=L):   transpose of (ef_lp + gelu(-dlm@vw1+vb1)@vw2 + ...)
//   PP (i>=L,j>=L):  0
// Fast path (vb1==0, detected at runtime): gelu(-u)=gelu(u)-u =>
//   out_pl = out_lp - dlm @ (vw1@vw2)   (W3, 3x32, precomputed)
// Round 3: wave-local main loop -- ALL LDS exchanges (dlmb/hef/hlp) are
//   intra-wave, so the 8 in-loop __syncthreads are removed (wave-synchronous
//   LDS, DS ops execute in issue order per wave). Only 2 barriers remain,
//   protecting the outb union in the epilogue. launch_bounds(256,3).
// ---------------------------------------------------------------------------

typedef __attribute__((__ext_vector_type__(8))) short bfrag;   // 8 x bf16 bits
typedef __attribute__((__ext_vector_type__(4))) float fx4;

#define MFMA_BF16(A, B, C) __builtin_amdgcn_mfma_f32_16x16x32_bf16((A), (B), (C), 0, 0, 0)

// workspace layout (float offsets)
#define OFF_ISTD 0      // 128: 1/(|std|+1e-5)
#define OFF_MS   128    // 128: mean * istd
#define OFF_C2   256    // 128: istd / sqrt(2*pi)
#define OFF_BIAS 384    // 32 : ob2 + vb2
#define OFF_W3   416    // 96 : W3[c][h] = sum_k vw1[c][k]*vw2[k][h]
#define OFF_FLAG 512    // 1  : int, 1 if vb1 all zero
#define WS_H_BASE 1024  // ushort region starts at float offset 1024
#define HOFF_OW1 0      // 16384 ushort, B-frag swizzled
#define HOFF_OW2 16384  // 4096
#define HOFF_VW2 20480  // 4096

#define N_MAIN 4096     // 1024 LL tiles + 3072 LP tiles
#define N_PP   2304     // zero-fill blocks
#define PP_ITERS 16
#define N_TOTAL (N_MAIN + N_PP)

__device__ __forceinline__ float rcp_f(float x) {
#if __has_builtin(__builtin_amdgcn_rcpf)
  return __builtin_amdgcn_rcpf(x);
#else
  return 1.0f / x;
#endif
}
__device__ __forceinline__ float exp2_f(float x) {
#if __has_builtin(__builtin_amdgcn_exp2f)
  return __builtin_amdgcn_exp2f(x);
#else
  return exp2f(x);
#endif
}
__device__ __forceinline__ unsigned short f2bf(float f) {  // RNE (setup only)
  unsigned u = __builtin_bit_cast(unsigned, f);
  return (unsigned short)((u + 0x7fffu + ((u >> 16) & 1u)) >> 16);
}
__device__ __forceinline__ unsigned short f2bf_fast(float f) {  // round-half-up, <=0.5 ulp
  unsigned u = __builtin_bit_cast(unsigned, f);
  return (unsigned short)((u + 0x8000u) >> 16);
}
// sigmoid-form GELU: x / (1 + exp2(x*(c0 + c1 x^2)))
__device__ __forceinline__ float gelu_t(float x) {
  float z = x * x;
  float p = x * __builtin_fmaf(z, -0.10294324f, -2.30220821f);  // -2u*log2(e)
  float e = exp2_f(p);
  return x * rcp_f(1.0f + e);
}

// ---------------------------------------------------------------------------
__global__ void setup_kernel(const float* __restrict__ means, const float* __restrict__ stds,
                             const float* __restrict__ ow1, const float* __restrict__ ow2,
                             const float* __restrict__ vw1, const float* __restrict__ vw2,
                             const float* __restrict__ ob2, const float* __restrict__ vb2,
                             const float* __restrict__ vb1, float* __restrict__ wsf) {
  int id = blockIdx.x * 256 + threadIdx.x;  // grid 16 -> 4096 threads
  unsigned short* wsh = (unsigned short*)(wsf + WS_H_BASE);

  if (id < 128) {
    float s = fabsf(stds[id]) + 1e-5f;
    float inv = 1.0f / s;
    wsf[OFF_ISTD + id] = inv;
    wsf[OFF_MS + id] = means[id] * inv;
    wsf[OFF_C2 + id] = inv * 0.3989422804f;  // 1/sqrt(2*pi)
  } else if (id < 160) {
    int h = id - 128;
    wsf[OFF_BIAS + h] = ob2[h] + vb2[h];
  } else if (id < 256) {
    int t = id - 160; int c = t >> 5, h = t & 31;
    float s = 0.0f;
    for (int k = 0; k < 128; ++k) s += vw1[c * 128 + k] * vw2[k * 32 + h];
    wsf[OFF_W3 + c * 32 + h] = s;
  } else if (id == 256) {
    int f = 1;
    for (int k = 0; k < 128; ++k) if (vb1[k] != 0.0f) f = 0;
    ((int*)wsf)[OFF_FLAG] = f;
  }
  // ow1 (128x128) -> B-frag layout: block=(n>>4)*4+(k>>5); in-block ((n&15)*4+((k>>3)&3))*8+(k&7)
  for (int idx = id; idx < 16384; idx += 4096) {
    int k = idx >> 7, n = idx & 127;
    int pos = ((n >> 4) * 4 + (k >> 5)) * 512 + ((n & 15) * 4 + ((k >> 3) & 3)) * 8 + (k & 7);
    wsh[HOFF_OW1 + pos] = f2bf(ow1[idx]);
  }
  // ow2 / vw2 (128x32)
  {
    int idx = id;  // exactly 4096 elements
    int k = idx >> 5, n = idx & 31;
    int pos = ((n >> 4) * 4 + (k >> 5)) * 512 + ((n & 15) * 4 + ((k >> 3) & 3)) * 8 + (k & 7);
    wsh[HOFF_OW2 + pos] = f2bf(ow2[idx]);
    wsh[HOFF_VW2 + pos] = f2bf(vw2[idx]);
  }
}

// ---------------------------------------------------------------------------
// decode interleaved block index: per group of 25 -> 16 main, 9 PP
__device__ __forceinline__ void decode_block(int bidx, bool& is_pp, int& sub) {
  int g = bidx / 25, r = bidx % 25;   // 256 groups
  if (r >= 16) { is_pp = true;  sub = g * 9 + (r - 16); }
  else         { is_pp = false; sub = g * 16 + r; }
}

__device__ __forceinline__ void pp_fill(int pp_id, float* __restrict__ out, int tid) {
  int id = pp_id * 256 + tid;  // 0..589823
  fx4 z = {0.f, 0.f, 0.f, 0.f};
#pragma unroll
  for (int i = 0; i < PP_ITERS; ++i) {
    int idx = id + i * 589824;          // total 9437184 float4s
    int c4 = idx % 192;
    int t2 = idx / 192;
    int r = t2 % 768;
    int bh = t2 / 768;                  // 0..63
    *(fx4*)(out + (((long)bh) << 20) + ((long)(256 + r) << 10) + 256 + c4 * 4) = z;
  }
}

// ---------------------------------------------------------------------------
// FAST kernel: requires vb1 == 0 (flag==1); else exits immediately.
__global__ __launch_bounds__(256, 3) void main_fast(
    const float* __restrict__ pos, const int* __restrict__ etyp,
    const float* __restrict__ mulw, const float* __restrict__ biasw,
    const float* __restrict__ ob1, const float* __restrict__ vw1,
    const float* __restrict__ wsf, float* __restrict__ out) {
  int flag = ((const int*)wsf)[OFF_FLAG];
  if (!flag) return;

  int tid = threadIdx.x;
  bool is_pp; int sub;
  decode_block(blockIdx.x, is_pp, sub);
  if (is_pp) { pp_fill(sub, out, tid); return; }

  const unsigned short* wsh = (const unsigned short*)(wsf + WS_H_BASE);
  __shared__ union {
    struct { unsigned short hef[4096]; unsigned short hlp[4096]; } s;
    float outb[4224];                   // [h][e] staging, stride 132 (epilogue)
  } u;
  __shared__ float dlmb[512];           // dlm per edge (stride 4), wave-local use

  int lane = tid & 63, w = tid >> 6;
  int q = lane >> 4, c15 = lane & 15;

  // tile decode: 128 edges = 8 rows x 16 cols
  int t = sub;
  int b, row0, col0;
  bool is_lp;
  if (t < 1024) {
    is_lp = false;
    b = t >> 9;
    int r = t & 511;                       // 32 row-tiles x 16 col-tiles
    row0 = (r >> 4) << 3;
    col0 = (r & 15) << 4;
  } else {
    is_lp = true;
    int t2 = t - 1024;
    b = t2 / 1536;
    int r = t2 % 1536;                     // 96 x 16
    row0 = 256 + ((r >> 4) << 3);
    col0 = (r & 15) << 4;
  }

  // ---- stage 1: gaussians directly into MFMA A-fragments (registers) ----
  // wave w owns edges e = 32w .. 32w+31 (rows 2w, 2w+1 of the 8x16 tile)
  bfrag gfr[2][4];
  float Ae[2];
  for (int mi = 0; mi < 2; ++mi) {
    int rloc = 2 * w + mi;
    int rowg = row0 + rloc, colg = col0 + c15;
    const float* pr = pos + ((b << 10) + rowg) * 3;
    const float* pc = pos + ((b << 10) + colg) * 3;
    float dx = pc[0] - pr[0], dy = pc[1] - pr[1], dz = pc[2] - pr[2];
    float d2 = __builtin_fmaf(dx, dx, __builtin_fmaf(dy, dy, dz * dz));
    float dist = rcp_f(d2 + 1.0f);
    int et = etyp[(b << 20) + (rowg << 10) + colg];
    Ae[mi] = __builtin_fmaf(mulw[et], dist, biasw[et]);
    if (q == 0) {  // wave-local write, consumed only by this wave
      int e = rloc * 16 + c15;
      dlmb[e * 4 + 0] = dx; dlmb[e * 4 + 1] = dy; dlmb[e * 4 + 2] = dz;
    }
  }
#pragma unroll
  for (int kc = 0; kc < 4; ++kc) {
    int k0 = kc * 32 + q * 8;
    fx4 is0 = *(const fx4*)(wsf + OFF_ISTD + k0);
    fx4 is1 = *(const fx4*)(wsf + OFF_ISTD + k0 + 4);
    fx4 ms0 = *(const fx4*)(wsf + OFF_MS + k0);
    fx4 ms1 = *(const fx4*)(wsf + OFF_MS + k0 + 4);
    fx4 cc0 = *(const fx4*)(wsf + OFF_C2 + k0);
    fx4 cc1 = *(const fx4*)(wsf + OFF_C2 + k0 + 4);
#pragma unroll
    for (int mi = 0; mi < 2; ++mi) {
      bfrag fr;
#pragma unroll
      for (int j = 0; j < 8; ++j) {
        float is = (j < 4) ? is0[j & 3] : is1[j & 3];
        float msv = (j < 4) ? ms0[j & 3] : ms1[j & 3];
        float ccv = (j < 4) ? cc0[j & 3] : cc1[j & 3];
        float y = __builtin_fmaf(Ae[mi], is, -msv);
        float g = exp2_f(y * y * (-0.72134752f)) * ccv;  // exp(-0.5 y^2)
        fr[j] = (short)f2bf_fast(g);
      }
      gfr[mi][kc] = fr;
    }
  }

  float ob1v[8];
#pragma unroll
  for (int i = 0; i < 8; ++i) ob1v[i] = ob1[i * 16 + c15];

  fx4 zero4 = {0.f, 0.f, 0.f, 0.f};
  fx4 aef[2][2], alp[2][2];
#pragma unroll
  for (int mi = 0; mi < 2; ++mi)
#pragma unroll
    for (int nh = 0; nh < 2; ++nh) { aef[mi][nh] = zero4; alp[mi][nh] = zero4; }

  int oct = lane & 3, eloc = lane >> 2;  // wave-local dlm-MLP mapping

  // ---- main loop over kk (hidden dim) chunks of 32 : NO barriers ----
  for (int c2 = 0; c2 < 4; ++c2) {
    // GEMM1: hidden[e][kk] for this chunk
    fx4 a1[2][2];
#pragma unroll
    for (int mi = 0; mi < 2; ++mi) { a1[mi][0] = zero4; a1[mi][1] = zero4; }
#pragma unroll
    for (int kc = 0; kc < 4; ++kc) {
      bfrag b0 = *(const bfrag*)(wsh + HOFF_OW1 + (((c2 * 2 + 0) * 4 + kc) * 512 + (c15 * 4 + q) * 8));
      bfrag b1 = *(const bfrag*)(wsh + HOFF_OW1 + (((c2 * 2 + 1) * 4 + kc) * 512 + (c15 * 4 + q) * 8));
      a1[0][0] = MFMA_BF16(gfr[0][kc], b0, a1[0][0]);
      a1[0][1] = MFMA_BF16(gfr[0][kc], b1, a1[0][1]);
      a1[1][0] = MFMA_BF16(gfr[1][kc], b0, a1[1][0]);
      a1[1][1] = MFMA_BF16(gfr[1][kc], b1, a1[1][1]);
    }
    // gelu(+ob1) -> bf16 scatter to LDS in A2-frag layout (wave-local region)
#pragma unroll
    for (int mi = 0; mi < 2; ++mi)
#pragma unroll
      for (int nt = 0; nt < 2; ++nt) {
        float bb = ob1v[c2 * 2 + nt];
#pragma unroll
        for (int r = 0; r < 4; ++r) {
          float v = gelu_t(a1[mi][nt][r] + bb);
          u.s.hef[(2 * w + mi) * 512 + ((q * 4 + r) * 4 + nt * 2 + ((lane >> 3) & 1)) * 8 + (lane & 7)] = f2bf_fast(v);
        }
      }
    // dlm-MLP hidden for this chunk (wave-local edges)
    {
      int kk0 = c2 * 32 + oct * 8;
      fx4 w1a0 = *(const fx4*)(vw1 + kk0);
      fx4 w1a1 = *(const fx4*)(vw1 + kk0 + 4);
      fx4 w1b0 = *(const fx4*)(vw1 + 128 + kk0);
      fx4 w1b1 = *(const fx4*)(vw1 + 128 + kk0 + 4);
      fx4 w1c0 = *(const fx4*)(vw1 + 256 + kk0);
      fx4 w1c1 = *(const fx4*)(vw1 + 256 + kk0 + 4);
#pragma unroll
      for (int mi = 0; mi < 2; ++mi) {
        int e = 32 * w + mi * 16 + eloc;   // owned by this wave
        float dx = dlmb[e * 4 + 0], dy = dlmb[e * 4 + 1], dz = dlmb[e * 4 + 2];
        bfrag fl;
#pragma unroll
        for (int j = 0; j < 8; ++j) {
          float wa = (j < 4) ? w1a0[j & 3] : w1a1[j & 3];
          float wb = (j < 4) ? w1b0[j & 3] : w1b1[j & 3];
          float wc = (j < 4) ? w1c0[j & 3] : w1c1[j & 3];
          float u0 = __builtin_fmaf(dx, wa, __builtin_fmaf(dy, wb, dz * wc));
          fl[j] = (short)f2bf_fast(gelu_t(u0));
        }
        *((bfrag*)(u.s.hlp + (2 * w + mi) * 512 + (eloc * 4 + oct) * 8)) = fl;
      }
    }
    // GEMM2: accumulate this 32-wide kk chunk (reads only this wave's LDS)
#pragma unroll
    for (int mi = 0; mi < 2; ++mi) {
      int mt = 2 * w + mi;
      bfrag a_ef = *(const bfrag*)(u.s.hef + mt * 512 + (c15 * 4 + q) * 8);
      bfrag a_lp = *(const bfrag*)(u.s.hlp + mt * 512 + (c15 * 4 + q) * 8);
#pragma unroll
      for (int nh = 0; nh < 2; ++nh) {
        bfrag b_o = *(const bfrag*)(wsh + HOFF_OW2 + ((nh * 4 + c2) * 512 + (c15 * 4 + q) * 8));
        bfrag b_v = *(const bfrag*)(wsh + HOFF_VW2 + ((nh * 4 + c2) * 512 + (c15 * 4 + q) * 8));
        aef[mi][nh] = MFMA_BF16(a_ef, b_o, aef[mi][nh]);
        alp[mi][nh] = MFMA_BF16(a_lp, b_v, alp[mi][nh]);
      }
    }
  }

  // ---- epilogue: out_lp = aef + alp + (ob2+vb2), staged via LDS [h][e] ----
  __syncthreads();  // all waves done reading hef/hlp before outb overwrites union
  float bs0 = wsf[OFF_BIAS + c15];
  float bs1 = wsf[OFF_BIAS + 16 + c15];
#pragma unroll
  for (int mi = 0; mi < 2; ++mi) {
    int mt = 2 * w + mi;
#pragma unroll
    for (int nh = 0; nh < 2; ++nh) {
      float bb = nh ? bs1 : bs0;
      fx4 v;
#pragma unroll
      for (int r = 0; r < 4; ++r) v[r] = aef[mi][nh][r] + alp[mi][nh][r] + bb;
      *(fx4*)(u.outb + (nh * 16 + c15) * 132 + mt * 16 + q * 4) = v;
    }
  }
  __syncthreads();

  long base = (((long)(b * 32)) << 20) + (((long)row0) << 10) + col0;
#pragma unroll
  for (int i = 0; i < 4; ++i) {
    int it = tid + (i << 8);
    int h = it >> 5, rr = (it >> 2) & 7, c4v = it & 3;
    fx4 v = *(const fx4*)(u.outb + h * 132 + rr * 16 + c4v * 4);
    *(fx4*)(out + base + (((long)h) << 20) + (rr << 10) + c4v * 4) = v;
  }

  if (is_lp) {
    // fast PL: out_pl = out_lp - dlm @ W3 (transposed write)
#pragma unroll
    for (int i = 0; i < 4; ++i) {
      int it = tid + (i << 8);
      int h = it >> 5, rr2 = (it >> 1) & 15, p4 = it & 1;
      float w30 = wsf[OFF_W3 + h];
      float w31 = wsf[OFF_W3 + 32 + h];
      float w32 = wsf[OFF_W3 + 64 + h];
      fx4 v;
#pragma unroll
      for (int k = 0; k < 4; ++k) {
        int e = (p4 * 4 + k) * 16 + rr2;
        float val = u.outb[h * 132 + e];
        float dx = dlmb[e * 4 + 0], dy = dlmb[e * 4 + 1], dz = dlmb[e * 4 + 2];
        v[k] = val - __builtin_fmaf(dx, w30, __builtin_fmaf(dy, w31, dz * w32));
      }
      *(fx4*)(out + (((long)(b * 32 + h)) << 20) + (((long)(col0 + rr2)) << 10) + row0 + p4 * 4) = v;
    }
  }
}

// ---------------------------------------------------------------------------
// GENERAL kernel: handles vb1 != 0 (flag==0); else exits immediately.
__global__ __launch_bounds__(256, 2) void main_general(
    const float* __restrict__ pos, const int* __restrict__ etyp,
    const float* __restrict__ mulw, const float* __restrict__ biasw,
    const float* __restrict__ ob1, const float* __restrict__ vw1,
    const float* __restrict__ vb1, const float* __restrict__ wsf,
    float* __restrict__ out) {
  int flag = ((const int*)wsf)[OFF_FLAG];
  if (flag) return;

  int tid = threadIdx.x;
  if (blockIdx.x >= N_MAIN) { pp_fill(blockIdx.x - N_MAIN, out, tid); return; }

  const unsigned short* wsh = (const unsigned short*)(wsf + WS_H_BASE);
  __shared__ unsigned short hef[4096];
  __shared__ unsigned short hlp[4096];
  __shared__ unsigned short hpl[4096];
  __shared__ float dlmb[512];
  __shared__ float outb[4224];

  int lane = tid & 63, w = tid >> 6;
  int q = lane >> 4, c15 = lane & 15;

  int t = blockIdx.x;
  int b, row0, col0;
  bool is_lp;
  if (t < 1024) {
    is_lp = false;
    b = t >> 9;
    int r = t & 511;
    row0 = (r >> 4) << 3;
    col0 = (r & 15) << 4;
  } else {
    is_lp = true;
    int t2 = t - 1024;
    b = t2 / 1536;
    int r = t2 % 1536;
    row0 = 256 + ((r >> 4) << 3);
    col0 = (r & 15) << 4;
  }

  bfrag gfr[2][4];
  float Ae[2];
  for (int mi = 0; mi < 2; ++mi) {
    int rloc = 2 * w + mi;
    int rowg = row0 + rloc, colg = col0 + c15;
    const float* pr = pos + ((b << 10) + rowg) * 3;
    const float* pc = pos + ((b << 10) + colg) * 3;
    float dx = pc[0] - pr[0], dy = pc[1] - pr[1], dz = pc[2] - pr[2];
    float d2 = __builtin_fmaf(dx, dx, __builtin_fmaf(dy, dy, dz * dz));
    float dist = rcp_f(d2 + 1.0f);
    int et = etyp[(b << 20) + (rowg << 10) + colg];
    Ae[mi] = __builtin_fmaf(mulw[et], dist, biasw[et]);
    if (q == 0) {
      int e = rloc * 16 + c15;
      dlmb[e * 4 + 0] = dx; dlmb[e * 4 + 1] = dy; dlmb[e * 4 + 2] = dz;
    }
  }
#pragma unroll
  for (int kc = 0; kc < 4; ++kc) {
    int k0 = kc * 32 + q * 8;
    fx4 is0 = *(const fx4*)(wsf + OFF_ISTD + k0);
    fx4 is1 = *(const fx4*)(wsf + OFF_ISTD + k0 + 4);
    fx4 ms0 = *(const fx4*)(wsf + OFF_MS + k0);
    fx4 ms1 = *(const fx4*)(wsf + OFF_MS + k0 + 4);
    fx4 cc0 = *(const fx4*)(wsf + OFF_C2 + k0);
    fx4 cc1 = *(const fx4*)(wsf + OFF_C2 + k0 + 4);
#pragma unroll
    for (int mi = 0; mi < 2; ++mi) {
      bfrag fr;
#pragma unroll
      for (int j = 0; j < 8; ++j) {
        float is = (j < 4) ? is0[j & 3] : is1[j & 3];
        float msv = (j < 4) ? ms0[j & 3] : ms1[j & 3];
        float ccv = (j < 4) ? cc0[j & 3] : cc1[j & 3];
        float y = __builtin_fmaf(Ae[mi], is, -msv);
        float g = exp2_f(y * y * (-0.72134752f)) * ccv;
        fr[j] = (short)f2bf(g);
      }
      gfr[mi][kc] = fr;
    }
  }
  __syncthreads();

  float ob1v[8];
#pragma unroll
  for (int i = 0; i < 8; ++i) ob1v[i] = ob1[i * 16 + c15];

  fx4 zero4 = {0.f, 0.f, 0.f, 0.f};
  fx4 aef[2][2], alp[2][2], apl[2][2];
#pragma unroll
  for (int mi = 0; mi < 2; ++mi)
#pragma unroll
    for (int nh = 0; nh < 2; ++nh) { aef[mi][nh] = zero4; alp[mi][nh] = zero4; apl[mi][nh] = zero4; }

  int oct = tid & 3, e0 = tid >> 2;

  for (int c2 = 0; c2 < 4; ++c2) {
    fx4 a1[2][2];
#pragma unroll
    for (int mi = 0; mi < 2; ++mi) { a1[mi][0] = zero4; a1[mi][1] = zero4; }
#pragma unroll
    for (int kc = 0; kc < 4; ++kc) {
      bfrag b0 = *(const bfrag*)(wsh + HOFF_OW1 + (((c2 * 2 + 0) * 4 + kc) * 512 + (c15 * 4 + q) * 8));
      bfrag b1 = *(const bfrag*)(wsh + HOFF_OW1 + (((c2 * 2 + 1) * 4 + kc) * 512 + (c15 * 4 + q) * 8));
      a1[0][0] = MFMA_BF16(gfr[0][kc], b0, a1[0][0]);
      a1[0][1] = MFMA_BF16(gfr[0][kc], b1, a1[0][1]);
      a1[1][0] = MFMA_BF16(gfr[1][kc], b0, a1[1][0]);
      a1[1][1] = MFMA_BF16(gfr[1][kc], b1, a1[1][1]);
    }
#pragma unroll
    for (int mi = 0; mi < 2; ++mi)
#pragma unroll
      for (int nt = 0; nt < 2; ++nt) {
        float bb = ob1v[c2 * 2 + nt];
#pragma unroll
        for (int r = 0; r < 4; ++r) {
          float v = gelu_t(a1[mi][nt][r] + bb);
          hef[(2 * w + mi) * 512 + ((q * 4 + r) * 4 + nt * 2 + ((lane >> 3) & 1)) * 8 + (lane & 7)] = f2bf(v);
        }
      }
    {
      int kk0 = c2 * 32 + oct * 8;
      fx4 w1a0 = *(const fx4*)(vw1 + kk0);
      fx4 w1a1 = *(const fx4*)(vw1 + kk0 + 4);
      fx4 w1b0 = *(const fx4*)(vw1 + 128 + kk0);
      fx4 w1b1 = *(const fx4*)(vw1 + 128 + kk0 + 4);
      fx4 w1c0 = *(const fx4*)(vw1 + 256 + kk0);
      fx4 w1c1 = *(const fx4*)(vw1 + 256 + kk0 + 4);
      fx4 vb0 = *(const fx4*)(vb1 + kk0);
      fx4 vb1q = *(const fx4*)(vb1 + kk0 + 4);
#pragma unroll
      for (int pass = 0; pass < 2; ++pass) {
        int e = e0 + (pass << 6);
        float dx = dlmb[e * 4 + 0], dy = dlmb[e * 4 + 1], dz = dlmb[e * 4 + 2];
        bfrag fl, fp;
#pragma unroll
        for (int j = 0; j < 8; ++j) {
          float wa = (j < 4) ? w1a0[j & 3] : w1a1[j & 3];
          float wb = (j < 4) ? w1b0[j & 3] : w1b1[j & 3];
          float wc = (j < 4) ? w1c0[j & 3] : w1c1[j & 3];
          float bb = (j < 4) ? vb0[j & 3] : vb1q[j & 3];
          float u0 = __builtin_fmaf(dx, wa, __builtin_fmaf(dy, wb, dz * wc));
          fl[j] = (short)f2bf(gelu_t(u0 + bb));
          fp[j] = (short)f2bf(gelu_t(bb - u0));
        }
        *((bfrag*)(hlp + (e >> 4) * 512 + ((e & 15) * 4 + oct) * 8)) = fl;
        *((bfrag*)(hpl + (e >> 4) * 512 + ((e & 15) * 4 + oct) * 8)) = fp;
      }
    }
    __syncthreads();
#pragma unroll
    for (int mi = 0; mi < 2; ++mi) {
      int mt = 2 * w + mi;
      bfrag a_ef = *(const bfrag*)(hef + mt * 512 + (c15 * 4 + q) * 8);
      bfrag a_lp = *(const bfrag*)(hlp + mt * 512 + (c15 * 4 + q) * 8);
      bfrag a_pl = *(const bfrag*)(hpl + mt * 512 + (c15 * 4 + q) * 8);
#pragma unroll
      for (int nh = 0; nh < 2; ++nh) {
        bfrag b_o = *(const bfrag*)(wsh + HOFF_OW2 + ((nh * 4 + c2) * 512 + (c15 * 4 + q) * 8));
        bfrag b_v = *(const bfrag*)(wsh + HOFF_VW2 + ((nh * 4 + c2) * 512 + (c15 * 4 + q) * 8));
        aef[mi][nh] = MFMA_BF16(a_ef, b_o, aef[mi][nh]);
        alp[mi][nh] = MFMA_BF16(a_lp, b_v, alp[mi][nh]);
        apl[mi][nh] = MFMA_BF16(a_pl, b_v, apl[mi][nh]);
      }
    }
    __syncthreads();
  }

  float bs0 = wsf[OFF_BIAS + c15];
  float bs1 = wsf[OFF_BIAS + 16 + c15];
#pragma unroll
  for (int mi = 0; mi < 2; ++mi) {
    int mt = 2 * w + mi;
#pragma unroll
    for (int nh = 0; nh < 2; ++nh) {
      float bb = nh ? bs1 : bs0;
      fx4 v;
#pragma unroll
      for (int r = 0; r < 4; ++r) v[r] = aef[mi][nh][r] + alp[mi][nh][r] + bb;
      *(fx4*)(outb + (nh * 16 + c15) * 132 + mt * 16 + q * 4) = v;
    }
  }
  __syncthreads();

  long base = (((long)(b * 32)) << 20) + (((long)row0) << 10) + col0;
#pragma unroll
  for (int i = 0; i < 4; ++i) {
    int it = tid + (i << 8);
    int h = it >> 5, rr = (it >> 2) & 7, c4v = it & 3;
    fx4 v = *(const fx4*)(outb + h * 132 + rr * 16 + c4v * 4);
    *(fx4*)(out + base + (((long)h) << 20) + (rr << 10) + c4v * 4) = v;
  }

  if (is_lp) {
    __syncthreads();
#pragma unroll
    for (int mi = 0; mi < 2; ++mi) {
      int mt = 2 * w + mi;
#pragma unroll
      for (int nh = 0; nh < 2; ++nh) {
        float bb = nh ? bs1 : bs0;
        fx4 v;
#pragma unroll
        for (int r = 0; r < 4; ++r) v[r] = aef[mi][nh][r] + apl[mi][nh][r] + bb;
        *(fx4*)(outb + (nh * 16 + c15) * 132 + mt * 16 + q * 4) = v;
      }
    }
    __syncthreads();
#pragma unroll
    for (int i = 0; i < 4; ++i) {
      int it = tid + (i << 8);
      int h = it >> 5, rr2 = (it >> 1) & 15, p4 = it & 1;
      fx4 v;
#pragma unroll
      for (int k = 0; k < 4; ++k) {
        int e = (p4 * 4 + k) * 16 + rr2;
        v[k] = outb[h * 132 + e];
      }
      *(fx4*)(out + (((long)(b * 32 + h)) << 20) + (((long)(col0 + rr2)) << 10) + row0 + p4 * 4) = v;
    }
  }
}

// ---------------------------------------------------------------------------
extern "C" void kernel_launch(void* const* d_in, const int* in_sizes, int n_in,
                              void* d_out, int out_size, void* d_ws, size_t ws_size,
                              hipStream_t stream) {
  const float* pos   = (const float*)d_in[0];
  const int*   etyp  = (const int*)d_in[1];
  // d_in[2] = protein_length (768, fixed by harness shapes)
  const float* means = (const float*)d_in[3];
  const float* stds  = (const float*)d_in[4];
  const float* mulw  = (const float*)d_in[5];
  const float* biasw = (const float*)d_in[6];
  const float* ow1   = (const float*)d_in[7];
  const float* ob1   = (const float*)d_in[8];
  const float* ow2   = (const float*)d_in[9];
  const float* ob2   = (const float*)d_in[10];
  const float* vw1   = (const float*)d_in[11];
  const float* vb1   = (const float*)d_in[12];
  const float* vw2   = (const float*)d_in[13];
  const float* vb2   = (const float*)d_in[14];
  float* out = (float*)d_out;
  float* wsf = (float*)d_ws;

  setup_kernel<<<dim3(16), dim3(256), 0, stream>>>(means, stds, ow1, ow2, vw1, vw2,
                                                   ob2, vb2, vb1, wsf);
  main_fast<<<dim3(N_TOTAL), dim3(256), 0, stream>>>(pos, etyp, mulw, biasw,
                                                     ob1, vw1, wsf, out);
  main_general<<<dim3(N_TOTAL), dim3(256), 0, stream>>>(pos, etyp, mulw, biasw,
                                                        ob1, vw1, vb1, wsf, out);
}

// Round 5
// 384.347 us; speedup vs baseline: 1.0682x; 1.0009x over previous
//
#include <hip/hip_runtime.h>
#include <math.h>

// ---------------------------------------------------------------------------
// DistanceBias fused kernel for MI355X (gfx950)
// out[b,h,i,j], B=2,H=32,N=1024, L=256 (ligand), P=768 (protein)
//   LL (i<L,j<L):    gelu(g@ow1+ob1)@ow2 + gelu(dlm@vw1+vb1)@vw2 + ob2+vb2
//   LP (i>=L,j<L):   same with row=protein point
//   PL (i<L,j>=L):   transpose of (ef_lp + gelu(-dlm@vw1+vb1)@vw2 + ...)
//   PP (i>=L,j>=L):  0
// Fast path (vb1==0, detected at runtime): gelu(-u)=gelu(u)-u =>
//   out_pl = out_lp - dlm @ (vw1@vw2)   (W3, 3x32, precomputed)
// Round 5: R4 resubmit with pkrtz return-type fix (__fp16 vector, not _Float16).
//   f16 MFMA pipeline, v_cvt_pkrtz_f16_f32 packing, float2 packed-FP32 math.
// ---------------------------------------------------------------------------

typedef __attribute__((__ext_vector_type__(2))) float fx2;
typedef __attribute__((__ext_vector_type__(4))) float fx4;
typedef __attribute__((__ext_vector_type__(2))) __fp16 fp16x2;
typedef __attribute__((__ext_vector_type__(8))) _Float16 hfrag;
typedef __attribute__((__ext_vector_type__(4))) unsigned int ux4;

#define MFMA_F16(A, B, C) \
  __builtin_amdgcn_mfma_f32_16x16x32_f16(__builtin_bit_cast(hfrag, (A)), \
                                         __builtin_bit_cast(hfrag, (B)), (C), 0, 0, 0)

// workspace layout (float offsets)
#define OFF_ISTD 0      // 128: 1/(|std|+1e-5)
#define OFF_MS   128    // 128: mean * istd
#define OFF_C2   256    // 128: istd / sqrt(2*pi)
#define OFF_BIAS 384    // 32 : ob2 + vb2
#define OFF_W3   416    // 96 : W3[c][h] = sum_k vw1[c][k]*vw2[k][h]
#define OFF_FLAG 512    // 1  : int, 1 if vb1 all zero
#define WS_H_BASE 1024  // ushort (f16 bits) region starts at float offset 1024
#define HOFF_OW1 0      // 16384 ushort, B-frag swizzled
#define HOFF_OW2 16384  // 4096
#define HOFF_VW2 20480  // 4096

#define N_MAIN 4096     // 1024 LL tiles + 3072 LP tiles
#define N_PP   2304     // zero-fill blocks
#define PP_ITERS 16
#define N_TOTAL (N_MAIN + N_PP)

__device__ __forceinline__ float rcp_f(float x) {
#if __has_builtin(__builtin_amdgcn_rcpf)
  return __builtin_amdgcn_rcpf(x);
#else
  return 1.0f / x;
#endif
}
__device__ __forceinline__ float exp2_f(float x) {
#if __has_builtin(__builtin_amdgcn_exp2f)
  return __builtin_amdgcn_exp2f(x);
#else
  return exp2f(x);
#endif
}
__device__ __forceinline__ unsigned pkrtz(float a, float b) {  // 2xf32 -> packed f16
  fp16x2 r = __builtin_amdgcn_cvt_pkrtz(a, b);
  return __builtin_bit_cast(unsigned, r);
}
__device__ __forceinline__ unsigned short f2h_s(float f) {  // scalar f32->f16 RNE
  _Float16 h = (_Float16)f;
  return __builtin_bit_cast(unsigned short, h);
}
// sigmoid-form GELU on a pair: x / (1 + exp2(x*(c0 + c1 x^2))), packed f16 out
__device__ __forceinline__ unsigned gelu2_pk(fx2 x) {
  fx2 z = x * x;                                           // v_pk_mul_f32
  fx2 p = x * (z * (-0.10294324f) + (-2.30220821f));       // pk fma/mul
  float d0 = 1.0f + exp2_f(p.x);
  float d1 = 1.0f + exp2_f(p.y);
  float g0 = x.x * rcp_f(d0);
  float g1 = x.y * rcp_f(d1);
  return pkrtz(g0, g1);
}
__device__ __forceinline__ float gelu_t(float x) {  // scalar (general kernel)
  float z = x * x;
  float p = x * __builtin_fmaf(z, -0.10294324f, -2.30220821f);
  float e = exp2_f(p);
  return x * rcp_f(1.0f + e);
}

// ---------------------------------------------------------------------------
__global__ void setup_kernel(const float* __restrict__ means, const float* __restrict__ stds,
                             const float* __restrict__ ow1, const float* __restrict__ ow2,
                             const float* __restrict__ vw1, const float* __restrict__ vw2,
                             const float* __restrict__ ob2, const float* __restrict__ vb2,
                             const float* __restrict__ vb1, float* __restrict__ wsf) {
  int id = blockIdx.x * 256 + threadIdx.x;  // grid 16 -> 4096 threads
  unsigned short* wsh = (unsigned short*)(wsf + WS_H_BASE);

  if (id < 128) {
    float s = fabsf(stds[id]) + 1e-5f;
    float inv = 1.0f / s;
    wsf[OFF_ISTD + id] = inv;
    wsf[OFF_MS + id] = means[id] * inv;
    wsf[OFF_C2 + id] = inv * 0.3989422804f;  // 1/sqrt(2*pi)
  } else if (id < 160) {
    int h = id - 128;
    wsf[OFF_BIAS + h] = ob2[h] + vb2[h];
  } else if (id < 256) {
    int t = id - 160; int c = t >> 5, h = t & 31;
    float s = 0.0f;
    for (int k = 0; k < 128; ++k) s += vw1[c * 128 + k] * vw2[k * 32 + h];
    wsf[OFF_W3 + c * 32 + h] = s;
  } else if (id == 256) {
    int f = 1;
    for (int k = 0; k < 128; ++k) if (vb1[k] != 0.0f) f = 0;
    ((int*)wsf)[OFF_FLAG] = f;
  }
  // ow1 (128x128) -> B-frag layout: block=(n>>4)*4+(k>>5); in-block ((n&15)*4+((k>>3)&3))*8+(k&7)
  for (int idx = id; idx < 16384; idx += 4096) {
    int k = idx >> 7, n = idx & 127;
    int pos = ((n >> 4) * 4 + (k >> 5)) * 512 + ((n & 15) * 4 + ((k >> 3) & 3)) * 8 + (k & 7);
    wsh[HOFF_OW1 + pos] = f2h_s(ow1[idx]);
  }
  // ow2 / vw2 (128x32)
  {
    int idx = id;  // exactly 4096 elements
    int k = idx >> 5, n = idx & 31;
    int pos = ((n >> 4) * 4 + (k >> 5)) * 512 + ((n & 15) * 4 + ((k >> 3) & 3)) * 8 + (k & 7);
    wsh[HOFF_OW2 + pos] = f2h_s(ow2[idx]);
    wsh[HOFF_VW2 + pos] = f2h_s(vw2[idx]);
  }
}

// ---------------------------------------------------------------------------
// decode interleaved block index: per group of 25 -> 16 main, 9 PP
__device__ __forceinline__ void decode_block(int bidx, bool& is_pp, int& sub) {
  int g = bidx / 25, r = bidx % 25;   // 256 groups
  if (r >= 16) { is_pp = true;  sub = g * 9 + (r - 16); }
  else         { is_pp = false; sub = g * 16 + r; }
}

__device__ __forceinline__ void pp_fill(int pp_id, float* __restrict__ out, int tid) {
  int id = pp_id * 256 + tid;  // 0..589823
  fx4 z = {0.f, 0.f, 0.f, 0.f};
#pragma unroll
  for (int i = 0; i < PP_ITERS; ++i) {
    int idx = id + i * 589824;          // total 9437184 float4s
    int c4 = idx % 192;
    int t2 = idx / 192;
    int r = t2 % 768;
    int bh = t2 / 768;                  // 0..63
    *(fx4*)(out + (((long)bh) << 20) + ((long)(256 + r) << 10) + 256 + c4 * 4) = z;
  }
}

// ---------------------------------------------------------------------------
// FAST kernel: requires vb1 == 0 (flag==1); else exits immediately.
__global__ __launch_bounds__(256, 3) void main_fast(
    const float* __restrict__ pos, const int* __restrict__ etyp,
    const float* __restrict__ mulw, const float* __restrict__ biasw,
    const float* __restrict__ ob1, const float* __restrict__ vw1,
    const float* __restrict__ wsf, float* __restrict__ out) {
  int flag = ((const int*)wsf)[OFF_FLAG];
  if (!flag) return;

  int tid = threadIdx.x;
  bool is_pp; int sub;
  decode_block(blockIdx.x, is_pp, sub);
  if (is_pp) { pp_fill(sub, out, tid); return; }

  const unsigned short* wsh = (const unsigned short*)(wsf + WS_H_BASE);
  __shared__ union {
    struct { unsigned short hef[4096]; unsigned short hlp[4096]; } s;
    float outb[4224];                   // [h][e] staging, stride 132 (epilogue)
  } u;
  __shared__ float dlmb[512];           // dlm per edge (stride 4), wave-local use

  int lane = tid & 63, w = tid >> 6;
  int q = lane >> 4, c15 = lane & 15;

  // tile decode: 128 edges = 8 rows x 16 cols
  int t = sub;
  int b, row0, col0;
  bool is_lp;
  if (t < 1024) {
    is_lp = false;
    b = t >> 9;
    int r = t & 511;                       // 32 row-tiles x 16 col-tiles
    row0 = (r >> 4) << 3;
    col0 = (r & 15) << 4;
  } else {
    is_lp = true;
    int t2 = t - 1024;
    b = t2 / 1536;
    int r = t2 % 1536;                     // 96 x 16
    row0 = 256 + ((r >> 4) << 3);
    col0 = (r & 15) << 4;
  }

  // ---- stage 1: gaussians directly into MFMA A-fragments (registers) ----
  // wave w owns edges e = 32w .. 32w+31 (rows 2w, 2w+1 of the 8x16 tile)
  ux4 gfr[2][4];
  float Ae[2];
  for (int mi = 0; mi < 2; ++mi) {
    int rloc = 2 * w + mi;
    int rowg = row0 + rloc, colg = col0 + c15;
    const float* pr = pos + ((b << 10) + rowg) * 3;
    const float* pc = pos + ((b << 10) + colg) * 3;
    float dx = pc[0] - pr[0], dy = pc[1] - pr[1], dz = pc[2] - pr[2];
    float d2 = __builtin_fmaf(dx, dx, __builtin_fmaf(dy, dy, dz * dz));
    float dist = rcp_f(d2 + 1.0f);
    int et = etyp[(b << 20) + (rowg << 10) + colg];
    Ae[mi] = __builtin_fmaf(mulw[et], dist, biasw[et]);
    if (q == 0) {  // wave-local write, consumed only by this wave
      int e = rloc * 16 + c15;
      dlmb[e * 4 + 0] = dx; dlmb[e * 4 + 1] = dy; dlmb[e * 4 + 2] = dz;
    }
  }
  const fx2* is2 = (const fx2*)(wsf + OFF_ISTD);
  const fx2* ms2 = (const fx2*)(wsf + OFF_MS);
  const fx2* cc2 = (const fx2*)(wsf + OFF_C2);
#pragma unroll
  for (int kc = 0; kc < 4; ++kc) {
    int p0 = (kc * 32 + q * 8) >> 1;  // fx2 index
#pragma unroll
    for (int mi = 0; mi < 2; ++mi) {
      ux4 fr;
#pragma unroll
      for (int p = 0; p < 4; ++p) {
        fx2 is = is2[p0 + p], ms = ms2[p0 + p], cc = cc2[p0 + p];
        fx2 y = Ae[mi] * is - ms;                 // v_pk_fma_f32
        fx2 ta = (y * y) * (-0.72134752f);        // exp(-0.5 y^2) = exp2(t)
        float g0 = exp2_f(ta.x), g1 = exp2_f(ta.y);
        fr[p] = pkrtz(g0 * cc.x, g1 * cc.y);
      }
      gfr[mi][kc] = fr;
    }
  }

  float ob1v[8];
#pragma unroll
  for (int i = 0; i < 8; ++i) ob1v[i] = ob1[i * 16 + c15];

  fx4 zero4 = {0.f, 0.f, 0.f, 0.f};
  fx4 aef[2][2], alp[2][2];
#pragma unroll
  for (int mi = 0; mi < 2; ++mi)
#pragma unroll
    for (int nh = 0; nh < 2; ++nh) { aef[mi][nh] = zero4; alp[mi][nh] = zero4; }

  int oct = lane & 3, eloc = lane >> 2;  // wave-local dlm-MLP mapping
  const fx2* vw1_2 = (const fx2*)vw1;

  // ---- main loop over kk (hidden dim) chunks of 32 : NO barriers ----
  for (int c2 = 0; c2 < 4; ++c2) {
    // GEMM1: hidden[e][kk] for this chunk
    fx4 a1[2][2];
#pragma unroll
    for (int mi = 0; mi < 2; ++mi) { a1[mi][0] = zero4; a1[mi][1] = zero4; }
#pragma unroll
    for (int kc = 0; kc < 4; ++kc) {
      ux4 b0 = *(const ux4*)(wsh + HOFF_OW1 + (((c2 * 2 + 0) * 4 + kc) * 512 + (c15 * 4 + q) * 8));
      ux4 b1 = *(const ux4*)(wsh + HOFF_OW1 + (((c2 * 2 + 1) * 4 + kc) * 512 + (c15 * 4 + q) * 8));
      a1[0][0] = MFMA_F16(gfr[0][kc], b0, a1[0][0]);
      a1[0][1] = MFMA_F16(gfr[0][kc], b1, a1[0][1]);
      a1[1][0] = MFMA_F16(gfr[1][kc], b0, a1[1][0]);
      a1[1][1] = MFMA_F16(gfr[1][kc], b1, a1[1][1]);
    }
    // gelu(+ob1) -> f16 scatter to LDS in A2-frag layout (wave-local region)
#pragma unroll
    for (int mi = 0; mi < 2; ++mi)
#pragma unroll
      for (int nt = 0; nt < 2; ++nt) {
        float bb = ob1v[c2 * 2 + nt];
        fx2 x01 = {a1[mi][nt][0] + bb, a1[mi][nt][1] + bb};
        fx2 x23 = {a1[mi][nt][2] + bb, a1[mi][nt][3] + bb};
        unsigned lo = gelu2_pk(x01);
        unsigned hi = gelu2_pk(x23);
        int hbase = (2 * w + mi) * 512 + (nt * 2 + ((lane >> 3) & 1)) * 8 + (lane & 7);
        u.s.hef[hbase + (q * 4 + 0) * 32] = (unsigned short)lo;
        u.s.hef[hbase + (q * 4 + 1) * 32] = (unsigned short)(lo >> 16);
        u.s.hef[hbase + (q * 4 + 2) * 32] = (unsigned short)hi;
        u.s.hef[hbase + (q * 4 + 3) * 32] = (unsigned short)(hi >> 16);
      }
    // dlm-MLP hidden for this chunk (wave-local edges), packed-pair math
    {
      int pk0 = (c2 * 32 + oct * 8) >> 1;  // fx2 index into vw1 rows
      fx2 wa[4], wb[4], wc[4];
#pragma unroll
      for (int p = 0; p < 4; ++p) {
        wa[p] = vw1_2[pk0 + p];
        wb[p] = vw1_2[64 + pk0 + p];
        wc[p] = vw1_2[128 + pk0 + p];
      }
#pragma unroll
      for (int mi = 0; mi < 2; ++mi) {
        int e = 32 * w + mi * 16 + eloc;   // owned by this wave
        fx4 d4 = *(const fx4*)(dlmb + e * 4);  // ds_read_b128
        ux4 fl;
#pragma unroll
        for (int p = 0; p < 4; ++p) {
          fx2 u0 = d4.x * wa[p] + d4.y * wb[p] + d4.z * wc[p];  // pk fma chain
          fl[p] = gelu2_pk(u0);
        }
        *((ux4*)(u.s.hlp + (2 * w + mi) * 512 + (eloc * 4 + oct) * 8)) = fl;
      }
    }
    // GEMM2: accumulate this 32-wide kk chunk (reads only this wave's LDS)
#pragma unroll
    for (int mi = 0; mi < 2; ++mi) {
      int mt = 2 * w + mi;
      ux4 a_ef = *(const ux4*)(u.s.hef + mt * 512 + (c15 * 4 + q) * 8);
      ux4 a_lp = *(const ux4*)(u.s.hlp + mt * 512 + (c15 * 4 + q) * 8);
#pragma unroll
      for (int nh = 0; nh < 2; ++nh) {
        ux4 b_o = *(const ux4*)(wsh + HOFF_OW2 + ((nh * 4 + c2) * 512 + (c15 * 4 + q) * 8));
        ux4 b_v = *(const ux4*)(wsh + HOFF_VW2 + ((nh * 4 + c2) * 512 + (c15 * 4 + q) * 8));
        aef[mi][nh] = MFMA_F16(a_ef, b_o, aef[mi][nh]);
        alp[mi][nh] = MFMA_F16(a_lp, b_v, alp[mi][nh]);
      }
    }
  }

  // ---- epilogue: out_lp = aef + alp + (ob2+vb2), staged via LDS [h][e] ----
  __syncthreads();  // all waves done with hef/hlp before outb overwrites union
  float bs0 = wsf[OFF_BIAS + c15];
  float bs1 = wsf[OFF_BIAS + 16 + c15];
#pragma unroll
  for (int mi = 0; mi < 2; ++mi) {
    int mt = 2 * w + mi;
#pragma unroll
    for (int nh = 0; nh < 2; ++nh) {
      float bb = nh ? bs1 : bs0;
      fx4 v;
#pragma unroll
      for (int r = 0; r < 4; ++r) v[r] = aef[mi][nh][r] + alp[mi][nh][r] + bb;
      *(fx4*)(u.outb + (nh * 16 + c15) * 132 + mt * 16 + q * 4) = v;
    }
  }
  __syncthreads();

  long base = (((long)(b * 32)) << 20) + (((long)row0) << 10) + col0;
#pragma unroll
  for (int i = 0; i < 4; ++i) {
    int it = tid + (i << 8);
    int h = it >> 5, rr = (it >> 2) & 7, c4v = it & 3;
    fx4 v = *(const fx4*)(u.outb + h * 132 + rr * 16 + c4v * 4);
    *(fx4*)(out + base + (((long)h) << 20) + (rr << 10) + c4v * 4) = v;
  }

  if (is_lp) {
    // fast PL: out_pl = out_lp - dlm @ W3 (transposed write)
#pragma unroll
    for (int i = 0; i < 4; ++i) {
      int it = tid + (i << 8);
      int h = it >> 5, rr2 = (it >> 1) & 15, p4 = it & 1;
      float w30 = wsf[OFF_W3 + h];
      float w31 = wsf[OFF_W3 + 32 + h];
      float w32 = wsf[OFF_W3 + 64 + h];
      fx4 v;
#pragma unroll
      for (int k = 0; k < 4; ++k) {
        int e = (p4 * 4 + k) * 16 + rr2;
        float val = u.outb[h * 132 + e];
        fx4 d4 = *(const fx4*)(dlmb + e * 4);
        v[k] = val - __builtin_fmaf(d4.x, w30, __builtin_fmaf(d4.y, w31, d4.z * w32));
      }
      *(fx4*)(out + (((long)(b * 32 + h)) << 20) + (((long)(col0 + rr2)) << 10) + row0 + p4 * 4) = v;
    }
  }
}

// ---------------------------------------------------------------------------
// GENERAL kernel: handles vb1 != 0 (flag==0); else exits immediately.
__global__ __launch_bounds__(256, 2) void main_general(
    const float* __restrict__ pos, const int* __restrict__ etyp,
    const float* __restrict__ mulw, const float* __restrict__ biasw,
    const float* __restrict__ ob1, const float* __restrict__ vw1,
    const float* __restrict__ vb1, const float* __restrict__ wsf,
    float* __restrict__ out) {
  int flag = ((const int*)wsf)[OFF_FLAG];
  if (flag) return;

  int tid = threadIdx.x;
  if (blockIdx.x >= N_MAIN) { pp_fill(blockIdx.x - N_MAIN, out, tid); return; }

  const unsigned short* wsh = (const unsigned short*)(wsf + WS_H_BASE);
  __shared__ unsigned short hef[4096];
  __shared__ unsigned short hlp[4096];
  __shared__ unsigned short hpl[4096];
  __shared__ float dlmb[512];
  __shared__ float outb[4224];

  int lane = tid & 63, w = tid >> 6;
  int q = lane >> 4, c15 = lane & 15;

  int t = blockIdx.x;
  int b, row0, col0;
  bool is_lp;
  if (t < 1024) {
    is_lp = false;
    b = t >> 9;
    int r = t & 511;
    row0 = (r >> 4) << 3;
    col0 = (r & 15) << 4;
  } else {
    is_lp = true;
    int t2 = t - 1024;
    b = t2 / 1536;
    int r = t2 % 1536;
    row0 = 256 + ((r >> 4) << 3);
    col0 = (r & 15) << 4;
  }

  ux4 gfr[2][4];
  float Ae[2];
  for (int mi = 0; mi < 2; ++mi) {
    int rloc = 2 * w + mi;
    int rowg = row0 + rloc, colg = col0 + c15;
    const float* pr = pos + ((b << 10) + rowg) * 3;
    const float* pc = pos + ((b << 10) + colg) * 3;
    float dx = pc[0] - pr[0], dy = pc[1] - pr[1], dz = pc[2] - pr[2];
    float d2 = __builtin_fmaf(dx, dx, __builtin_fmaf(dy, dy, dz * dz));
    float dist = rcp_f(d2 + 1.0f);
    int et = etyp[(b << 20) + (rowg << 10) + colg];
    Ae[mi] = __builtin_fmaf(mulw[et], dist, biasw[et]);
    if (q == 0) {
      int e = rloc * 16 + c15;
      dlmb[e * 4 + 0] = dx; dlmb[e * 4 + 1] = dy; dlmb[e * 4 + 2] = dz;
    }
  }
  const fx2* is2 = (const fx2*)(wsf + OFF_ISTD);
  const fx2* ms2 = (const fx2*)(wsf + OFF_MS);
  const fx2* cc2 = (const fx2*)(wsf + OFF_C2);
#pragma unroll
  for (int kc = 0; kc < 4; ++kc) {
    int p0 = (kc * 32 + q * 8) >> 1;
#pragma unroll
    for (int mi = 0; mi < 2; ++mi) {
      ux4 fr;
#pragma unroll
      for (int p = 0; p < 4; ++p) {
        fx2 is = is2[p0 + p], ms = ms2[p0 + p], cc = cc2[p0 + p];
        fx2 y = Ae[mi] * is - ms;
        fx2 ta = (y * y) * (-0.72134752f);
        float g0 = exp2_f(ta.x), g1 = exp2_f(ta.y);
        fr[p] = pkrtz(g0 * cc.x, g1 * cc.y);
      }
      gfr[mi][kc] = fr;
    }
  }
  __syncthreads();

  float ob1v[8];
#pragma unroll
  for (int i = 0; i < 8; ++i) ob1v[i] = ob1[i * 16 + c15];

  fx4 zero4 = {0.f, 0.f, 0.f, 0.f};
  fx4 aef[2][2], alp[2][2], apl[2][2];
#pragma unroll
  for (int mi = 0; mi < 2; ++mi)
#pragma unroll
    for (int nh = 0; nh < 2; ++nh) { aef[mi][nh] = zero4; alp[mi][nh] = zero4; apl[mi][nh] = zero4; }

  int oct = tid & 3, e0 = tid >> 2;

  for (int c2 = 0; c2 < 4; ++c2) {
    fx4 a1[2][2];
#pragma unroll
    for (int mi = 0; mi < 2; ++mi) { a1[mi][0] = zero4; a1[mi][1] = zero4; }
#pragma unroll
    for (int kc = 0; kc < 4; ++kc) {
      ux4 b0 = *(const ux4*)(wsh + HOFF_OW1 + (((c2 * 2 + 0) * 4 + kc) * 512 + (c15 * 4 + q) * 8));
      ux4 b1 = *(const ux4*)(wsh + HOFF_OW1 + (((c2 * 2 + 1) * 4 + kc) * 512 + (c15 * 4 + q) * 8));
      a1[0][0] = MFMA_F16(gfr[0][kc], b0, a1[0][0]);
      a1[0][1] = MFMA_F16(gfr[0][kc], b1, a1[0][1]);
      a1[1][0] = MFMA_F16(gfr[1][kc], b0, a1[1][0]);
      a1[1][1] = MFMA_F16(gfr[1][kc], b1, a1[1][1]);
    }
#pragma unroll
    for (int mi = 0; mi < 2; ++mi)
#pragma unroll
      for (int nt = 0; nt < 2; ++nt) {
        float bb = ob1v[c2 * 2 + nt];
#pragma unroll
        for (int r = 0; r < 4; ++r) {
          float v = gelu_t(a1[mi][nt][r] + bb);
          hef[(2 * w + mi) * 512 + ((q * 4 + r) * 4 + nt * 2 + ((lane >> 3) & 1)) * 8 + (lane & 7)] = f2h_s(v);
        }
      }
    {
      int kk0 = c2 * 32 + oct * 8;
      fx4 w1a0 = *(const fx4*)(vw1 + kk0);
      fx4 w1a1 = *(const fx4*)(vw1 + kk0 + 4);
      fx4 w1b0 = *(const fx4*)(vw1 + 128 + kk0);
      fx4 w1b1 = *(const fx4*)(vw1 + 128 + kk0 + 4);
      fx4 w1c0 = *(const fx4*)(vw1 + 256 + kk0);
      fx4 w1c1 = *(const fx4*)(vw1 + 256 + kk0 + 4);
      fx4 vb0 = *(const fx4*)(vb1 + kk0);
      fx4 vb1q = *(const fx4*)(vb1 + kk0 + 4);
#pragma unroll
      for (int pass = 0; pass < 2; ++pass) {
        int e = e0 + (pass << 6);
        float dx = dlmb[e * 4 + 0], dy = dlmb[e * 4 + 1], dz = dlmb[e * 4 + 2];
        unsigned short fl[8], fp[8];
#pragma unroll
        for (int j = 0; j < 8; ++j) {
          float wa = (j < 4) ? w1a0[j & 3] : w1a1[j & 3];
          float wb = (j < 4) ? w1b0[j & 3] : w1b1[j & 3];
          float wc = (j < 4) ? w1c0[j & 3] : w1c1[j & 3];
          float bb = (j < 4) ? vb0[j & 3] : vb1q[j & 3];
          float u0 = __builtin_fmaf(dx, wa, __builtin_fmaf(dy, wb, dz * wc));
          fl[j] = f2h_s(gelu_t(u0 + bb));
          fp[j] = f2h_s(gelu_t(bb - u0));
        }
#pragma unroll
        for (int j = 0; j < 8; ++j) {
          hlp[(e >> 4) * 512 + ((e & 15) * 4 + oct) * 8 + j] = fl[j];
          hpl[(e >> 4) * 512 + ((e & 15) * 4 + oct) * 8 + j] = fp[j];
        }
      }
    }
    __syncthreads();
#pragma unroll
    for (int mi = 0; mi < 2; ++mi) {
      int mt = 2 * w + mi;
      ux4 a_ef = *(const ux4*)(hef + mt * 512 + (c15 * 4 + q) * 8);
      ux4 a_lp = *(const ux4*)(hlp + mt * 512 + (c15 * 4 + q) * 8);
      ux4 a_pl = *(const ux4*)(hpl + mt * 512 + (c15 * 4 + q) * 8);
#pragma unroll
      for (int nh = 0; nh < 2; ++nh) {
        ux4 b_o = *(const ux4*)(wsh + HOFF_OW2 + ((nh * 4 + c2) * 512 + (c15 * 4 + q) * 8));
        ux4 b_v = *(const ux4*)(wsh + HOFF_VW2 + ((nh * 4 + c2) * 512 + (c15 * 4 + q) * 8));
        aef[mi][nh] = MFMA_F16(a_ef, b_o, aef[mi][nh]);
        alp[mi][nh] = MFMA_F16(a_lp, b_v, alp[mi][nh]);
        apl[mi][nh] = MFMA_F16(a_pl, b_v, apl[mi][nh]);
      }
    }
    __syncthreads();
  }

  float bs0 = wsf[OFF_BIAS + c15];
  float bs1 = wsf[OFF_BIAS + 16 + c15];
#pragma unroll
  for (int mi = 0; mi < 2; ++mi) {
    int mt = 2 * w + mi;
#pragma unroll
    for (int nh = 0; nh < 2; ++nh) {
      float bb = nh ? bs1 : bs0;
      fx4 v;
#pragma unroll
      for (int r = 0; r < 4; ++r) v[r] = aef[mi][nh][r] + alp[mi][nh][r] + bb;
      *(fx4*)(outb + (nh * 16 + c15) * 132 + mt * 16 + q * 4) = v;
    }
  }
  __syncthreads();

  long base = (((long)(b * 32)) << 20) + (((long)row0) << 10) + col0;
#pragma unroll
  for (int i = 0; i < 4; ++i) {
    int it = tid + (i << 8);
    int h = it >> 5, rr = (it >> 2) & 7, c4v = it & 3;
    fx4 v = *(const fx4*)(outb + h * 132 + rr * 16 + c4v * 4);
    *(fx4*)(out + base + (((long)h) << 20) + (rr << 10) + c4v * 4) = v;
  }

  if (is_lp) {
    __syncthreads();
#pragma unroll
    for (int mi = 0; mi < 2; ++mi) {
      int mt = 2 * w + mi;
#pragma unroll
      for (int nh = 0; nh < 2; ++nh) {
        float bb = nh ? bs1 : bs0;
        fx4 v;
#pragma unroll
        for (int r = 0; r < 4; ++r) v[r] = aef[mi][nh][r] + apl[mi][nh][r] + bb;
        *(fx4*)(outb + (nh * 16 + c15) * 132 + mt * 16 + q * 4) = v;
      }
    }
    __syncthreads();
#pragma unroll
    for (int i = 0; i < 4; ++i) {
      int it = tid + (i << 8);
      int h = it >> 5, rr2 = (it >> 1) & 15, p4 = it & 1;
      fx4 v;
#pragma unroll
      for (int k = 0; k < 4; ++k) {
        int e = (p4 * 4 + k) * 16 + rr2;
        v[k] = outb[h * 132 + e];
      }
      *(fx4*)(out + (((long)(b * 32 + h)) << 20) + (((long)(col0 + rr2)) << 10) + row0 + p4 * 4) = v;
    }
  }
}

// ---------------------------------------------------------------------------
extern "C" void kernel_launch(void* const* d_in, const int* in_sizes, int n_in,
                              void* d_out, int out_size, void* d_ws, size_t ws_size,
                              hipStream_t stream) {
  const float* pos   = (const float*)d_in[0];
  const int*   etyp  = (const int*)d_in[1];
  // d_in[2] = protein_length (768, fixed by harness shapes)
  const float* means = (const float*)d_in[3];
  const float* stds  = (const float*)d_in[4];
  const float* mulw  = (const float*)d_in[5];
  const float* biasw = (const float*)d_in[6];
  const float* ow1   = (const float*)d_in[7];
  const float* ob1   = (const float*)d_in[8];
  const float* ow2   = (const float*)d_in[9];
  const float* ob2   = (const float*)d_in[10];
  const float* vw1   = (const float*)d_in[11];
  const float* vb1   = (const float*)d_in[12];
  const float* vw2   = (const float*)d_in[13];
  const float* vb2   = (const float*)d_in[14];
  float* out = (float*)d_out;
  float* wsf = (float*)d_ws;

  setup_kernel<<<dim3(16), dim3(256), 0, stream>>>(means, stds, ow1, ow2, vw1, vw2,
                                                   ob2, vb2, vb1, wsf);
  main_fast<<<dim3(N_TOTAL), dim3(256), 0, stream>>>(pos, etyp, mulw, biasw,
                                                     ob1, vw1, wsf, out);
  main_general<<<dim3(N_TOTAL), dim3(256), 0, stream>>>(pos, etyp, mulw, biasw,
                                                        ob1, vw1, vb1, wsf, out);
}